// Round 2
// baseline (2353.935 us; speedup 1.0000x reference)
//
#include <hip/hip_runtime.h>
#include <math.h>

#define NBROWS 262144

// d_ws layout (floats):
// [0,1024)      S1_ss   : c0*(w1_ss[uvw]+w1_ss[vuw]) for u<v, c0*w for u==v  (M=8,W=16)
// [1024,2048)   S1_vv0  : same with c0/sqrt(3)
// [2048,3072)   C1_sv   : c1/sqrt(3)*(w1_sv[uvw]+w1_vs[vuw])
// [3072,4096)   A1_vv1  : c1/sqrt(6)*(w1_vv1[uvw]-w1_vv1[vuw]) for u<v
// [4096,6144)   S2_ss   (M=16,W=8)
// [6144,8192)   S2_vv0
// [8192,10240)  C2_sv
// [10240,12288) A2_vv1

__global__ __launch_bounds__(256) void prep_kernel(
    const float* __restrict__ w1_ss, const float* __restrict__ w1_vv0,
    const float* __restrict__ w1_sv, const float* __restrict__ w1_vs,
    const float* __restrict__ w1_vv1,
    const float* __restrict__ w2_ss, const float* __restrict__ w2_vv0,
    const float* __restrict__ w2_sv, const float* __restrict__ w2_vs,
    const float* __restrict__ w2_vv1,
    float* __restrict__ ws)
{
    const float inv3 = 0.5773502691896258f;
    const float inv6 = 0.4082482904638631f;
    int i = blockIdx.x * 256 + threadIdx.x;
    if (i >= 12288) return;
    float val = 0.f;
    if (i < 4096) {
        const float c0 = 0.08838834764831845f;   // 1/sqrt(8*8+8*8)
        const float c1 = 0.125f;                  // sqrt(3/(2*64+64))
        int a = i >> 10, r = i & 1023;
        int w = r & 15, uv = r >> 4, u = uv >> 3, vq = uv & 7;
        int tr = (vq * 8 + u) * 16 + w;           // transposed (v,u) index
        if (a == 0)      val = (u < vq) ? c0 * (w1_ss[r] + w1_ss[tr]) : ((u == vq) ? c0 * w1_ss[r] : 0.f);
        else if (a == 1) { const float cc = c0 * inv3;
                           val = (u < vq) ? cc * (w1_vv0[r] + w1_vv0[tr]) : ((u == vq) ? cc * w1_vv0[r] : 0.f); }
        else if (a == 2) val = (c1 * inv3) * (w1_sv[r] + w1_vs[tr]);
        else             val = (u < vq) ? (c1 * inv6) * (w1_vv1[r] - w1_vv1[tr]) : 0.f;
    } else {
        const float c0 = 0.04419417382415922f;   // 1/sqrt(16*16+16*16)
        const float c1 = 0.0625f;                 // sqrt(3/(2*256+256))
        int j = i - 4096;
        int a = j >> 11, r = j & 2047;
        int w = r & 7, uv = r >> 3, u = uv >> 4, vq = uv & 15;
        int tr = (vq * 16 + u) * 8 + w;
        if (a == 0)      val = (u < vq) ? c0 * (w2_ss[r] + w2_ss[tr]) : ((u == vq) ? c0 * w2_ss[r] : 0.f);
        else if (a == 1) { const float cc = c0 * inv3;
                           val = (u < vq) ? cc * (w2_vv0[r] + w2_vv0[tr]) : ((u == vq) ? cc * w2_vv0[r] : 0.f); }
        else if (a == 2) val = (c1 * inv3) * (w2_sv[r] + w2_vs[tr]);
        else             val = (u < vq) ? (c1 * inv6) * (w2_vv1[r] - w2_vv1[tr]) : 0.f;
    }
    ws[i] = val;
}

// fctp with LDS-resident folded weights; all weight reads are float4 at
// wave-uniform addresses (broadcast, conflict-free, base+imm offsets).
template<int M, int W>
__device__ __forceinline__ void fctp_lds(
    const float* Sss, const float* Svv0,
    const float* Csv, const float* Avv1,
    const float (&s)[M], const float (&v)[M][3],
    float (&os)[W], float (&ov)[W][3])
{
#pragma unroll
    for (int w = 0; w < W; ++w) { os[w] = 0.f; ov[w][0] = 0.f; ov[w][1] = 0.f; ov[w][2] = 0.f; }

    // scalar output: ss + vv0 paths (symmetrized weights, triangular loop)
#pragma unroll
    for (int u = 0; u < M; ++u) {
#pragma unroll
        for (int vv = u; vv < M; ++vv) {
            float p = s[u] * s[vv];
            float d = v[u][0]*v[vv][0] + v[u][1]*v[vv][1] + v[u][2]*v[vv][2];
            const float4* pss = reinterpret_cast<const float4*>(Sss  + (u*M+vv)*W);
            const float4* pvv = reinterpret_cast<const float4*>(Svv0 + (u*M+vv)*W);
#pragma unroll
            for (int w4 = 0; w4 < W/4; ++w4) {
                float4 a = pss[w4], b = pvv[w4];
                os[4*w4+0] += p * a.x + d * b.x;
                os[4*w4+1] += p * a.y + d * b.y;
                os[4*w4+2] += p * a.z + d * b.z;
                os[4*w4+3] += p * a.w + d * b.w;
            }
        }
    }

    // vector output: combined sv+vs path. t[w] = sum_u s[u]*Wc[u,vv,w], contiguous reads.
#pragma unroll
    for (int vv = 0; vv < M; ++vv) {
        float t[W];
#pragma unroll
        for (int w = 0; w < W; ++w) t[w] = 0.f;
#pragma unroll
        for (int u = 0; u < M; ++u) {
            const float4* pc = reinterpret_cast<const float4*>(Csv + (u*M+vv)*W);
            float su = s[u];
#pragma unroll
            for (int w4 = 0; w4 < W/4; ++w4) {
                float4 a = pc[w4];
                t[4*w4+0] += su * a.x;
                t[4*w4+1] += su * a.y;
                t[4*w4+2] += su * a.z;
                t[4*w4+3] += su * a.w;
            }
        }
#pragma unroll
        for (int w = 0; w < W; ++w) {
            ov[w][0] += t[w] * v[vv][0];
            ov[w][1] += t[w] * v[vv][1];
            ov[w][2] += t[w] * v[vv][2];
        }
    }

    // vector output: vv1 cross-product path (antisymmetrized weights, u<v)
#pragma unroll
    for (int u = 0; u < M; ++u) {
#pragma unroll
        for (int vv = u + 1; vv < M; ++vv) {
            float cx = v[u][1]*v[vv][2] - v[u][2]*v[vv][1];
            float cy = v[u][2]*v[vv][0] - v[u][0]*v[vv][2];
            float cz = v[u][0]*v[vv][1] - v[u][1]*v[vv][0];
            const float4* pa = reinterpret_cast<const float4*>(Avv1 + (u*M+vv)*W);
#pragma unroll
            for (int w4 = 0; w4 < W/4; ++w4) {
                float4 a = pa[w4];
                ov[4*w4+0][0] += a.x * cx; ov[4*w4+0][1] += a.x * cy; ov[4*w4+0][2] += a.x * cz;
                ov[4*w4+1][0] += a.y * cx; ov[4*w4+1][1] += a.y * cy; ov[4*w4+1][2] += a.y * cz;
                ov[4*w4+2][0] += a.z * cx; ov[4*w4+2][1] += a.z * cy; ov[4*w4+2][2] += a.z * cz;
                ov[4*w4+3][0] += a.w * cx; ov[4*w4+3][1] += a.w * cy; ov[4*w4+3][2] += a.w * cz;
            }
        }
    }
}

template<int N>
__device__ __forceinline__ void si_norm_dev(float (&ys)[N], float (&yv)[N][3])
{
    float sum = 0.f;
#pragma unroll
    for (int i = 0; i < N; ++i) sum += ys[i];
    float m = sum * (1.f / N);
    float var = 0.f;
#pragma unroll
    for (int i = 0; i < N; ++i) { float dd = ys[i] - m; var += dd * dd; }
    float stds = sqrtf(var * (1.f / (N - 1)));
    float invs = 1.f / (stds + 1e-9f);
#pragma unroll
    for (int i = 0; i < N; ++i) ys[i] *= invs;

    float n1[N];
    float sumn = 0.f;
#pragma unroll
    for (int i = 0; i < N; ++i) {
        n1[i] = sqrtf(yv[i][0]*yv[i][0] + yv[i][1]*yv[i][1] + yv[i][2]*yv[i][2] + 1e-9f);
        sumn += n1[i];
    }
    float mn = sumn * (1.f / N);
    float varn = 0.f;
#pragma unroll
    for (int i = 0; i < N; ++i) { float dd = n1[i] - mn; varn += dd * dd; }
    float stdv = sqrtf(varn * (1.f / (N - 1)));
    float invv = 1.f / (stdv + 1e-9f);
#pragma unroll
    for (int i = 0; i < N; ++i) { yv[i][0] *= invv; yv[i][1] *= invv; yv[i][2] *= invv; }
}

template<int N>
__device__ __forceinline__ void tv_norm_dev(float (&xs)[N], float (&xv)[N][3])
{
    float ss = 0.f;
#pragma unroll
    for (int i = 0; i < N; ++i) ss += xs[i]*xs[i];
    float invs = 1.f / sqrtf(ss + 1e-6f);
#pragma unroll
    for (int i = 0; i < N; ++i) xs[i] *= invs;
    float a0 = 0.f, a1 = 0.f, a2 = 0.f;
#pragma unroll
    for (int i = 0; i < N; ++i) { a0 += xv[i][0]*xv[i][0]; a1 += xv[i][1]*xv[i][1]; a2 += xv[i][2]*xv[i][2]; }
    float nm = (sqrtf(a0 + 1e-6f) + sqrtf(a1 + 1e-6f) + sqrtf(a2 + 1e-6f)) * (1.f / 3.f);
    float invv = 1.f / (nm + 1e-6f);
#pragma unroll
    for (int i = 0; i < N; ++i) { xv[i][0] *= invv; xv[i][1] *= invv; xv[i][2] *= invv; }
}

__global__ __launch_bounds__(256, 3) void DoubleLayer_main_kernel(
    const float* __restrict__ x,
    const float* __restrict__ ws,
    float* __restrict__ out)
{
    __shared__ float W[12288];
    // cooperative load: 3072 float4 across 256 threads
#pragma unroll
    for (int i = 0; i < 12; ++i) {
        int idx = threadIdx.x + i * 256;
        reinterpret_cast<float4*>(W)[idx] = reinterpret_cast<const float4*>(ws)[idx];
    }
    __syncthreads();

    int row = blockIdx.x * 256 + threadIdx.x;
    const float4* xr = reinterpret_cast<const float4*>(x + (size_t)row * 32);
    float4 q0 = xr[0], q1 = xr[1], q2 = xr[2], q3 = xr[3];
    float4 q4 = xr[4], q5 = xr[5], q6 = xr[6], q7 = xr[7];

    float s1[8];
    s1[0] = tanhf(q0.x); s1[1] = tanhf(q0.y); s1[2] = tanhf(q0.z); s1[3] = tanhf(q0.w);
    s1[4] = tanhf(q1.x); s1[5] = tanhf(q1.y); s1[6] = tanhf(q1.z); s1[7] = tanhf(q1.w);
    float v1[8][3];
    v1[0][0]=q2.x; v1[0][1]=q2.y; v1[0][2]=q2.z;
    v1[1][0]=q2.w; v1[1][1]=q3.x; v1[1][2]=q3.y;
    v1[2][0]=q3.z; v1[2][1]=q3.w; v1[2][2]=q4.x;
    v1[3][0]=q4.y; v1[3][1]=q4.z; v1[3][2]=q4.w;
    v1[4][0]=q5.x; v1[4][1]=q5.y; v1[4][2]=q5.z;
    v1[5][0]=q5.w; v1[5][1]=q6.x; v1[5][2]=q6.y;
    v1[6][0]=q6.z; v1[6][1]=q6.w; v1[6][2]=q7.x;
    v1[7][0]=q7.y; v1[7][1]=q7.z; v1[7][2]=q7.w;

    float ys[16], yv[16][3];
    fctp_lds<8,16>(W + 0, W + 1024, W + 2048, W + 3072, s1, v1, ys, yv);
    si_norm_dev<16>(ys, yv);
    tv_norm_dev<16>(ys, yv);

    float zs[8], zv[8][3];
    fctp_lds<16,8>(W + 4096, W + 6144, W + 8192, W + 10240, ys, yv, zs, zv);
    si_norm_dev<8>(zs, zv);

    float o[32];
#pragma unroll
    for (int w = 0; w < 8; ++w) o[w] = 1.f / (1.f + expf(-zs[w]));
#pragma unroll
    for (int w = 0; w < 8; ++w) {
        o[8 + 3*w + 0] = zv[w][0];
        o[8 + 3*w + 1] = zv[w][1];
        o[8 + 3*w + 2] = zv[w][2];
    }
    float4* orow = reinterpret_cast<float4*>(out + (size_t)row * 32);
#pragma unroll
    for (int i = 0; i < 8; ++i) orow[i] = make_float4(o[4*i+0], o[4*i+1], o[4*i+2], o[4*i+3]);
}

extern "C" void kernel_launch(void* const* d_in, const int* in_sizes, int n_in,
                              void* d_out, int out_size, void* d_ws, size_t ws_size,
                              hipStream_t stream)
{
    const float* x = (const float*)d_in[0];
    float* ws = (float*)d_ws;
    prep_kernel<<<48, 256, 0, stream>>>(
        (const float*)d_in[1], (const float*)d_in[2], (const float*)d_in[3],
        (const float*)d_in[4], (const float*)d_in[5],
        (const float*)d_in[6], (const float*)d_in[7], (const float*)d_in[8],
        (const float*)d_in[9], (const float*)d_in[10], ws);
    DoubleLayer_main_kernel<<<NBROWS/256, 256, 0, stream>>>(x, ws, (float*)d_out);
}

// Round 3
// 1886.351 us; speedup vs baseline: 1.2479x; 1.2479x over previous
//
#include <hip/hip_runtime.h>
#include <math.h>

#define NBROWS 262144

// d_ws layout (floats):
// [0,1024)      S1_ss   : c0*(w1_ss[uvw]+w1_ss[vuw]) for u<v, c0*w for u==v  (M=8,W=16)
// [1024,2048)   S1_vv0  : same with c0/sqrt(3)
// [2048,3072)   C1_sv   : c1/sqrt(3)*(w1_sv[uvw]+w1_vs[vuw])
// [3072,4096)   A1_vv1  : c1/sqrt(6)*(w1_vv1[uvw]-w1_vv1[vuw]) for u<v
// [4096,6144)   S2_ss   (M=16,W=8)
// [6144,8192)   S2_vv0
// [8192,10240)  C2_sv
// [10240,12288) A2_vv1

__global__ __launch_bounds__(256) void prep_kernel(
    const float* __restrict__ w1_ss, const float* __restrict__ w1_vv0,
    const float* __restrict__ w1_sv, const float* __restrict__ w1_vs,
    const float* __restrict__ w1_vv1,
    const float* __restrict__ w2_ss, const float* __restrict__ w2_vv0,
    const float* __restrict__ w2_sv, const float* __restrict__ w2_vs,
    const float* __restrict__ w2_vv1,
    float* __restrict__ ws)
{
    const float inv3 = 0.5773502691896258f;
    const float inv6 = 0.4082482904638631f;
    int i = blockIdx.x * 256 + threadIdx.x;
    if (i >= 12288) return;
    float val = 0.f;
    if (i < 4096) {
        const float c0 = 0.08838834764831845f;   // 1/sqrt(8*8+8*8)
        const float c1 = 0.125f;                  // sqrt(3/(2*64+64))
        int a = i >> 10, r = i & 1023;
        int w = r & 15, uv = r >> 4, u = uv >> 3, vq = uv & 7;
        int tr = (vq * 8 + u) * 16 + w;           // transposed (v,u) index
        if (a == 0)      val = (u < vq) ? c0 * (w1_ss[r] + w1_ss[tr]) : ((u == vq) ? c0 * w1_ss[r] : 0.f);
        else if (a == 1) { const float cc = c0 * inv3;
                           val = (u < vq) ? cc * (w1_vv0[r] + w1_vv0[tr]) : ((u == vq) ? cc * w1_vv0[r] : 0.f); }
        else if (a == 2) val = (c1 * inv3) * (w1_sv[r] + w1_vs[tr]);
        else             val = (u < vq) ? (c1 * inv6) * (w1_vv1[r] - w1_vv1[tr]) : 0.f;
    } else {
        const float c0 = 0.04419417382415922f;   // 1/sqrt(16*16+16*16)
        const float c1 = 0.0625f;                 // sqrt(3/(2*256+256))
        int j = i - 4096;
        int a = j >> 11, r = j & 2047;
        int w = r & 7, uv = r >> 3, u = uv >> 4, vq = uv & 15;
        int tr = (vq * 16 + u) * 8 + w;
        if (a == 0)      val = (u < vq) ? c0 * (w2_ss[r] + w2_ss[tr]) : ((u == vq) ? c0 * w2_ss[r] : 0.f);
        else if (a == 1) { const float cc = c0 * inv3;
                           val = (u < vq) ? cc * (w2_vv0[r] + w2_vv0[tr]) : ((u == vq) ? cc * w2_vv0[r] : 0.f); }
        else if (a == 2) val = (c1 * inv3) * (w2_sv[r] + w2_vs[tr]);
        else             val = (u < vq) ? (c1 * inv6) * (w2_vv1[r] - w2_vv1[tr]) : 0.f;
    }
    ws[i] = val;
}

// fctp with LDS-resident folded weights; all weight reads are float4 at
// wave-uniform addresses (broadcast, conflict-free, base+imm offsets).
template<int M, int W>
__device__ __forceinline__ void fctp_lds(
    const float* Sss, const float* Svv0,
    const float* Csv, const float* Avv1,
    const float (&s)[M], const float (&v)[M][3],
    float (&os)[W], float (&ov)[W][3])
{
#pragma unroll
    for (int w = 0; w < W; ++w) { os[w] = 0.f; ov[w][0] = 0.f; ov[w][1] = 0.f; ov[w][2] = 0.f; }

    // scalar output: ss + vv0 paths (symmetrized weights, triangular loop)
#pragma unroll
    for (int u = 0; u < M; ++u) {
#pragma unroll
        for (int vv = u; vv < M; ++vv) {
            float p = s[u] * s[vv];
            float d = v[u][0]*v[vv][0] + v[u][1]*v[vv][1] + v[u][2]*v[vv][2];
            const float4* pss = reinterpret_cast<const float4*>(Sss  + (u*M+vv)*W);
            const float4* pvv = reinterpret_cast<const float4*>(Svv0 + (u*M+vv)*W);
#pragma unroll
            for (int w4 = 0; w4 < W/4; ++w4) {
                float4 a = pss[w4], b = pvv[w4];
                os[4*w4+0] += p * a.x + d * b.x;
                os[4*w4+1] += p * a.y + d * b.y;
                os[4*w4+2] += p * a.z + d * b.z;
                os[4*w4+3] += p * a.w + d * b.w;
            }
        }
    }

    // vector output: combined sv+vs path. t[w] = sum_u s[u]*Wc[u,vv,w], contiguous reads.
#pragma unroll
    for (int vv = 0; vv < M; ++vv) {
        float t[W];
#pragma unroll
        for (int w = 0; w < W; ++w) t[w] = 0.f;
#pragma unroll
        for (int u = 0; u < M; ++u) {
            const float4* pc = reinterpret_cast<const float4*>(Csv + (u*M+vv)*W);
            float su = s[u];
#pragma unroll
            for (int w4 = 0; w4 < W/4; ++w4) {
                float4 a = pc[w4];
                t[4*w4+0] += su * a.x;
                t[4*w4+1] += su * a.y;
                t[4*w4+2] += su * a.z;
                t[4*w4+3] += su * a.w;
            }
        }
#pragma unroll
        for (int w = 0; w < W; ++w) {
            ov[w][0] += t[w] * v[vv][0];
            ov[w][1] += t[w] * v[vv][1];
            ov[w][2] += t[w] * v[vv][2];
        }
    }

    // vector output: vv1 cross-product path (antisymmetrized weights, u<v)
#pragma unroll
    for (int u = 0; u < M; ++u) {
#pragma unroll
        for (int vv = u + 1; vv < M; ++vv) {
            float cx = v[u][1]*v[vv][2] - v[u][2]*v[vv][1];
            float cy = v[u][2]*v[vv][0] - v[u][0]*v[vv][2];
            float cz = v[u][0]*v[vv][1] - v[u][1]*v[vv][0];
            const float4* pa = reinterpret_cast<const float4*>(Avv1 + (u*M+vv)*W);
#pragma unroll
            for (int w4 = 0; w4 < W/4; ++w4) {
                float4 a = pa[w4];
                ov[4*w4+0][0] += a.x * cx; ov[4*w4+0][1] += a.x * cy; ov[4*w4+0][2] += a.x * cz;
                ov[4*w4+1][0] += a.y * cx; ov[4*w4+1][1] += a.y * cy; ov[4*w4+1][2] += a.y * cz;
                ov[4*w4+2][0] += a.z * cx; ov[4*w4+2][1] += a.z * cy; ov[4*w4+2][2] += a.z * cz;
                ov[4*w4+3][0] += a.w * cx; ov[4*w4+3][1] += a.w * cy; ov[4*w4+3][2] += a.w * cz;
            }
        }
    }
}

template<int N>
__device__ __forceinline__ void si_norm_dev(float (&ys)[N], float (&yv)[N][3])
{
    float sum = 0.f;
#pragma unroll
    for (int i = 0; i < N; ++i) sum += ys[i];
    float m = sum * (1.f / N);
    float var = 0.f;
#pragma unroll
    for (int i = 0; i < N; ++i) { float dd = ys[i] - m; var += dd * dd; }
    float stds = sqrtf(var * (1.f / (N - 1)));
    float invs = 1.f / (stds + 1e-9f);
#pragma unroll
    for (int i = 0; i < N; ++i) ys[i] *= invs;

    float n1[N];
    float sumn = 0.f;
#pragma unroll
    for (int i = 0; i < N; ++i) {
        n1[i] = sqrtf(yv[i][0]*yv[i][0] + yv[i][1]*yv[i][1] + yv[i][2]*yv[i][2] + 1e-9f);
        sumn += n1[i];
    }
    float mn = sumn * (1.f / N);
    float varn = 0.f;
#pragma unroll
    for (int i = 0; i < N; ++i) { float dd = n1[i] - mn; varn += dd * dd; }
    float stdv = sqrtf(varn * (1.f / (N - 1)));
    float invv = 1.f / (stdv + 1e-9f);
#pragma unroll
    for (int i = 0; i < N; ++i) { yv[i][0] *= invv; yv[i][1] *= invv; yv[i][2] *= invv; }
}

template<int N>
__device__ __forceinline__ void tv_norm_dev(float (&xs)[N], float (&xv)[N][3])
{
    float ss = 0.f;
#pragma unroll
    for (int i = 0; i < N; ++i) ss += xs[i]*xs[i];
    float invs = 1.f / sqrtf(ss + 1e-6f);
#pragma unroll
    for (int i = 0; i < N; ++i) xs[i] *= invs;
    float a0 = 0.f, a1 = 0.f, a2 = 0.f;
#pragma unroll
    for (int i = 0; i < N; ++i) { a0 += xv[i][0]*xv[i][0]; a1 += xv[i][1]*xv[i][1]; a2 += xv[i][2]*xv[i][2]; }
    float nm = (sqrtf(a0 + 1e-6f) + sqrtf(a1 + 1e-6f) + sqrtf(a2 + 1e-6f)) * (1.f / 3.f);
    float invv = 1.f / (nm + 1e-6f);
#pragma unroll
    for (int i = 0; i < N; ++i) { xv[i][0] *= invv; xv[i][1] *= invv; xv[i][2] *= invv; }
}

// NOTE: __launch_bounds__(256) ONLY — no min-waves clause. Round 2 showed that
// a waves-per-EU floor (256,3) makes the allocator demote the per-thread
// arrays to scratch (7.4 GB of HBM traffic, VALUBusy 4.5%). Default budget
// (256 VGPR) keeps the ~130-float live set in registers.
__global__ __launch_bounds__(256) void DoubleLayer_main_kernel(
    const float* __restrict__ x,
    const float* __restrict__ ws,
    float* __restrict__ out)
{
    __shared__ float W[12288];

    int row = blockIdx.x * 256 + threadIdx.x;
    const float4* xr = reinterpret_cast<const float4*>(x + (size_t)row * 32);
    float4 q0 = xr[0], q1 = xr[1], q2 = xr[2], q3 = xr[3];
    float4 q4 = xr[4], q5 = xr[5], q6 = xr[6], q7 = xr[7];

    // cooperative weight stage: 3072 float4 across 256 threads
#pragma unroll
    for (int i = 0; i < 12; ++i) {
        int idx = threadIdx.x + i * 256;
        reinterpret_cast<float4*>(W)[idx] = reinterpret_cast<const float4*>(ws)[idx];
    }
    __syncthreads();

    float s1[8];
    s1[0] = tanhf(q0.x); s1[1] = tanhf(q0.y); s1[2] = tanhf(q0.z); s1[3] = tanhf(q0.w);
    s1[4] = tanhf(q1.x); s1[5] = tanhf(q1.y); s1[6] = tanhf(q1.z); s1[7] = tanhf(q1.w);
    float v1[8][3];
    v1[0][0]=q2.x; v1[0][1]=q2.y; v1[0][2]=q2.z;
    v1[1][0]=q2.w; v1[1][1]=q3.x; v1[1][2]=q3.y;
    v1[2][0]=q3.z; v1[2][1]=q3.w; v1[2][2]=q4.x;
    v1[3][0]=q4.y; v1[3][1]=q4.z; v1[3][2]=q4.w;
    v1[4][0]=q5.x; v1[4][1]=q5.y; v1[4][2]=q5.z;
    v1[5][0]=q5.w; v1[5][1]=q6.x; v1[5][2]=q6.y;
    v1[6][0]=q6.z; v1[6][1]=q6.w; v1[6][2]=q7.x;
    v1[7][0]=q7.y; v1[7][1]=q7.z; v1[7][2]=q7.w;

    float ys[16], yv[16][3];
    fctp_lds<8,16>(W + 0, W + 1024, W + 2048, W + 3072, s1, v1, ys, yv);
    si_norm_dev<16>(ys, yv);
    tv_norm_dev<16>(ys, yv);

    float zs[8], zv[8][3];
    fctp_lds<16,8>(W + 4096, W + 6144, W + 8192, W + 10240, ys, yv, zs, zv);
    si_norm_dev<8>(zs, zv);

    float o[32];
#pragma unroll
    for (int w = 0; w < 8; ++w) o[w] = 1.f / (1.f + expf(-zs[w]));
#pragma unroll
    for (int w = 0; w < 8; ++w) {
        o[8 + 3*w + 0] = zv[w][0];
        o[8 + 3*w + 1] = zv[w][1];
        o[8 + 3*w + 2] = zv[w][2];
    }
    float4* orow = reinterpret_cast<float4*>(out + (size_t)row * 32);
#pragma unroll
    for (int i = 0; i < 8; ++i) orow[i] = make_float4(o[4*i+0], o[4*i+1], o[4*i+2], o[4*i+3]);
}

extern "C" void kernel_launch(void* const* d_in, const int* in_sizes, int n_in,
                              void* d_out, int out_size, void* d_ws, size_t ws_size,
                              hipStream_t stream)
{
    const float* x = (const float*)d_in[0];
    float* ws = (float*)d_ws;
    prep_kernel<<<48, 256, 0, stream>>>(
        (const float*)d_in[1], (const float*)d_in[2], (const float*)d_in[3],
        (const float*)d_in[4], (const float*)d_in[5],
        (const float*)d_in[6], (const float*)d_in[7], (const float*)d_in[8],
        (const float*)d_in[9], (const float*)d_in[10], ws);
    DoubleLayer_main_kernel<<<NBROWS/256, 256, 0, stream>>>(x, ws, (float*)d_out);
}

// Round 4
// 261.501 us; speedup vs baseline: 9.0016x; 7.2136x over previous
//
#include <hip/hip_runtime.h>
#include <math.h>

#define NBROWS 262144

// d_ws layout (floats):
// [0,2048)      P1 : interleaved {Sss,Svv0} for layer1, idx ((u*8+v)*16+w)*2+{0,1}
//               Sss = c0*(w_ss[uvw]+w_ss[vuw]) u<v / c0*w diag / 0 u>v; Svv0 same *1/sqrt3
// [2048,3072)   C1 : c1/sqrt3*(w_sv[uvw]+w_vs[vuw])          (full ordered)
// [3072,4096)   A1 : c1/sqrt6*(w_vv1[uvw]-w_vv1[vuw]) u<v else 0
// [4096,8192)   P2 : interleaved {Sss,Svv0} layer2, idx ((u*16+v)*8+w)*2+{0,1}
// [8192,10240)  C2
// [10240,12288) A2

__global__ __launch_bounds__(256) void prep_kernel(
    const float* __restrict__ w1_ss, const float* __restrict__ w1_vv0,
    const float* __restrict__ w1_sv, const float* __restrict__ w1_vs,
    const float* __restrict__ w1_vv1,
    const float* __restrict__ w2_ss, const float* __restrict__ w2_vv0,
    const float* __restrict__ w2_sv, const float* __restrict__ w2_vs,
    const float* __restrict__ w2_vv1,
    float* __restrict__ ws)
{
    const float inv3 = 0.5773502691896258f;
    const float inv6 = 0.4082482904638631f;
    int i = blockIdx.x * 256 + threadIdx.x;
    if (i >= 12288) return;
    float val = 0.f;
    if (i < 2048) {                       // P1 interleaved
        int which = i & 1, r = i >> 1;
        int w = r & 15, uv = r >> 4, u = uv >> 3, v = uv & 7;
        int tr = (v * 8 + u) * 16 + w;
        const float c0 = 0.08838834764831845f;   // 1/sqrt(64+64)
        const float* src = which ? w1_vv0 : w1_ss;
        float cc = which ? c0 * inv3 : c0;
        val = (u < v) ? cc * (src[r] + src[tr]) : ((u == v) ? cc * src[r] : 0.f);
    } else if (i < 3072) {                // C1
        int r = i - 2048;
        int w = r & 15, uv = r >> 4, u = uv >> 3, v = uv & 7;
        int tr = (v * 8 + u) * 16 + w; (void)u;
        const float c1 = 0.125f;                  // sqrt(3/(128+64))
        val = (c1 * inv3) * (w1_sv[r] + w1_vs[tr]);
    } else if (i < 4096) {                // A1
        int r = i - 3072;
        int w = r & 15, uv = r >> 4, u = uv >> 3, v = uv & 7;
        int tr = (v * 8 + u) * 16 + w;
        const float c1 = 0.125f;
        val = (u < v) ? (c1 * inv6) * (w1_vv1[r] - w1_vv1[tr]) : 0.f;
    } else if (i < 8192) {                // P2 interleaved
        int j = i - 4096;
        int which = j & 1, r = j >> 1;
        int w = r & 7, uv = r >> 3, u = uv >> 4, v = uv & 15;
        int tr = (v * 16 + u) * 8 + w;
        const float c0 = 0.04419417382415922f;   // 1/sqrt(256+256)
        const float* src = which ? w2_vv0 : w2_ss;
        float cc = which ? c0 * inv3 : c0;
        val = (u < v) ? cc * (src[r] + src[tr]) : ((u == v) ? cc * src[r] : 0.f);
    } else if (i < 10240) {               // C2
        int r = i - 8192;
        int w = r & 7, uv = r >> 3, u = uv >> 4, v = uv & 15;
        int tr = (v * 16 + u) * 8 + w; (void)u;
        const float c1 = 0.0625f;                 // sqrt(3/(512+256))
        val = (c1 * inv3) * (w2_sv[r] + w2_vs[tr]);
    } else {                              // A2
        int r = i - 10240;
        int w = r & 7, uv = r >> 3, u = uv >> 4, v = uv & 15;
        int tr = (v * 16 + u) * 8 + w;
        const float c1 = 0.0625f;
        val = (u < v) ? (c1 * inv6) * (w2_vv1[r] - w2_vv1[tr]) : 0.f;
    }
    ws[i] = val;
}

// One output-chunk [W0, W0+WC) of the folded tensor product.
// P = interleaved {Sss,Svv0} (read as float2/b64), C, A scalar b32.
// All weight addresses wave-uniform (broadcast), compile-time offsets.
// Accumulates into os[W0+w], ov[W0+w] (NS-sized arrays, compile-time indices).
template<int M, int W, int W0, int WC, int NS>
__device__ __forceinline__ void fctp_chunk(
    const float* P, const float* C, const float* A,
    const float (&s)[M], const float (&v)[M][3],
    float (&os)[NS], float (&ov)[NS][3])
{
#pragma unroll
    for (int w = 0; w < WC; ++w) {
        os[W0 + w] = 0.f;
        ov[W0 + w][0] = 0.f; ov[W0 + w][1] = 0.f; ov[W0 + w][2] = 0.f;
    }
    const float2* Pp = reinterpret_cast<const float2*>(P);
    // symmetric paths: ss + vv0 (triangular incl. diagonal)
#pragma unroll
    for (int u = 0; u < M; ++u) {
#pragma unroll
        for (int vv = u; vv < M; ++vv) {
            float p = s[u] * s[vv];
            float d = v[u][0]*v[vv][0] + v[u][1]*v[vv][1] + v[u][2]*v[vv][2];
#pragma unroll
            for (int w = 0; w < WC; ++w) {
                float2 t = Pp[(u*M + vv)*W + W0 + w];
                os[W0 + w] += p * t.x + d * t.y;
            }
        }
    }
    // sv+vs combined path: tw[w] = sum_u s[u]*C[u,vv,w], then apply * v[vv]
#pragma unroll
    for (int vv = 0; vv < M; ++vv) {
        float tw[WC];
#pragma unroll
        for (int w = 0; w < WC; ++w) tw[w] = 0.f;
#pragma unroll
        for (int u = 0; u < M; ++u) {
            float su = s[u];
#pragma unroll
            for (int w = 0; w < WC; ++w) tw[w] += su * C[(u*M + vv)*W + W0 + w];
        }
#pragma unroll
        for (int w = 0; w < WC; ++w) {
            ov[W0 + w][0] += tw[w] * v[vv][0];
            ov[W0 + w][1] += tw[w] * v[vv][1];
            ov[W0 + w][2] += tw[w] * v[vv][2];
        }
    }
    // antisymmetric cross-product path (u<v)
#pragma unroll
    for (int u = 0; u < M; ++u) {
#pragma unroll
        for (int vv = u + 1; vv < M; ++vv) {
            float cx = v[u][1]*v[vv][2] - v[u][2]*v[vv][1];
            float cy = v[u][2]*v[vv][0] - v[u][0]*v[vv][2];
            float cz = v[u][0]*v[vv][1] - v[u][1]*v[vv][0];
#pragma unroll
            for (int w = 0; w < WC; ++w) {
                float a = A[(u*M + vv)*W + W0 + w];
                ov[W0 + w][0] += a * cx;
                ov[W0 + w][1] += a * cy;
                ov[W0 + w][2] += a * cz;
            }
        }
    }
}

template<int N>
__device__ __forceinline__ void si_norm_dev(float (&ys)[N], float (&yv)[N][3])
{
    float sum = 0.f;
#pragma unroll
    for (int i = 0; i < N; ++i) sum += ys[i];
    float m = sum * (1.f / N);
    float var = 0.f;
#pragma unroll
    for (int i = 0; i < N; ++i) { float dd = ys[i] - m; var += dd * dd; }
    float invs = 1.f / (sqrtf(var * (1.f / (N - 1))) + 1e-9f);
#pragma unroll
    for (int i = 0; i < N; ++i) ys[i] *= invs;

    float n1[N];
    float sumn = 0.f;
#pragma unroll
    for (int i = 0; i < N; ++i) {
        n1[i] = sqrtf(yv[i][0]*yv[i][0] + yv[i][1]*yv[i][1] + yv[i][2]*yv[i][2] + 1e-9f);
        sumn += n1[i];
    }
    float mn = sumn * (1.f / N);
    float varn = 0.f;
#pragma unroll
    for (int i = 0; i < N; ++i) { float dd = n1[i] - mn; varn += dd * dd; }
    float invv = 1.f / (sqrtf(varn * (1.f / (N - 1))) + 1e-9f);
#pragma unroll
    for (int i = 0; i < N; ++i) { yv[i][0] *= invv; yv[i][1] *= invv; yv[i][2] *= invv; }
}

template<int N>
__device__ __forceinline__ void tv_norm_dev(float (&xs)[N], float (&xv)[N][3])
{
    float ss = 0.f;
#pragma unroll
    for (int i = 0; i < N; ++i) ss += xs[i]*xs[i];
    float invs = 1.f / sqrtf(ss + 1e-6f);
#pragma unroll
    for (int i = 0; i < N; ++i) xs[i] *= invs;
    float a0 = 0.f, a1 = 0.f, a2 = 0.f;
#pragma unroll
    for (int i = 0; i < N; ++i) { a0 += xv[i][0]*xv[i][0]; a1 += xv[i][1]*xv[i][1]; a2 += xv[i][2]*xv[i][2]; }
    float nm = (sqrtf(a0 + 1e-6f) + sqrtf(a1 + 1e-6f) + sqrtf(a2 + 1e-6f)) * (1.f / 3.f);
    float invv = 1.f / (nm + 1e-6f);
#pragma unroll
    for (int i = 0; i < N; ++i) { xv[i][0] *= invv; xv[i][1] *= invv; xv[i][2] *= invv; }
}

__device__ __forceinline__ float fast_tanh(float x) {
    // tanh(x) = 1 - 2/(exp(2x)+1)
    return 1.f - 2.f / (__expf(2.f * x) + 1.f);
}

// __launch_bounds__(256) only — no min-waves clause (R2: (256,3) demoted arrays
// to scratch). Chunked accumulation + b32/b64 LDS weight reads + sched_barrier
// phase fences keep worst-phase live set ~110 floats.
__global__ __launch_bounds__(256) void DoubleLayer_main_kernel(
    const float* __restrict__ x,
    const float* __restrict__ ws,
    float* __restrict__ out)
{
    __shared__ float Wl[12288];

    int row = blockIdx.x * 256 + threadIdx.x;
    const float4* xr = reinterpret_cast<const float4*>(x + (size_t)row * 32);
    float4 q0 = xr[0], q1 = xr[1], q2 = xr[2], q3 = xr[3];
    float4 q4 = xr[4], q5 = xr[5], q6 = xr[6], q7 = xr[7];

    // cooperative weight stage: 3072 float4 across 256 threads
#pragma unroll
    for (int i = 0; i < 12; ++i) {
        int idx = threadIdx.x + i * 256;
        reinterpret_cast<float4*>(Wl)[idx] = reinterpret_cast<const float4*>(ws)[idx];
    }
    __syncthreads();

    float s1[8];
    s1[0] = fast_tanh(q0.x); s1[1] = fast_tanh(q0.y); s1[2] = fast_tanh(q0.z); s1[3] = fast_tanh(q0.w);
    s1[4] = fast_tanh(q1.x); s1[5] = fast_tanh(q1.y); s1[6] = fast_tanh(q1.z); s1[7] = fast_tanh(q1.w);
    float v1[8][3];
    v1[0][0]=q2.x; v1[0][1]=q2.y; v1[0][2]=q2.z;
    v1[1][0]=q2.w; v1[1][1]=q3.x; v1[1][2]=q3.y;
    v1[2][0]=q3.z; v1[2][1]=q3.w; v1[2][2]=q4.x;
    v1[3][0]=q4.y; v1[3][1]=q4.z; v1[3][2]=q4.w;
    v1[4][0]=q5.x; v1[4][1]=q5.y; v1[4][2]=q5.z;
    v1[5][0]=q5.w; v1[5][1]=q6.x; v1[5][2]=q6.y;
    v1[6][0]=q6.z; v1[6][1]=q6.w; v1[6][2]=q7.x;
    v1[7][0]=q7.y; v1[7][1]=q7.z; v1[7][2]=q7.w;

    float ys[16], yv[16][3];
    fctp_chunk<8,16,0,8,16>(Wl + 0, Wl + 2048, Wl + 3072, s1, v1, ys, yv);
    __builtin_amdgcn_sched_barrier(0);
    fctp_chunk<8,16,8,8,16>(Wl + 0, Wl + 2048, Wl + 3072, s1, v1, ys, yv);
    __builtin_amdgcn_sched_barrier(0);

    si_norm_dev<16>(ys, yv);
    tv_norm_dev<16>(ys, yv);
    __builtin_amdgcn_sched_barrier(0);

    float zs[8], zv[8][3];
    fctp_chunk<16,8,0,8,8>(Wl + 4096, Wl + 8192, Wl + 10240, ys, yv, zs, zv);
    __builtin_amdgcn_sched_barrier(0);

    si_norm_dev<8>(zs, zv);

    float o[32];
#pragma unroll
    for (int w = 0; w < 8; ++w) o[w] = 1.f / (1.f + __expf(-zs[w]));
#pragma unroll
    for (int w = 0; w < 8; ++w) {
        o[8 + 3*w + 0] = zv[w][0];
        o[8 + 3*w + 1] = zv[w][1];
        o[8 + 3*w + 2] = zv[w][2];
    }
    float4* orow = reinterpret_cast<float4*>(out + (size_t)row * 32);
#pragma unroll
    for (int i = 0; i < 8; ++i) orow[i] = make_float4(o[4*i+0], o[4*i+1], o[4*i+2], o[4*i+3]);
}

extern "C" void kernel_launch(void* const* d_in, const int* in_sizes, int n_in,
                              void* d_out, int out_size, void* d_ws, size_t ws_size,
                              hipStream_t stream)
{
    const float* x = (const float*)d_in[0];
    float* ws = (float*)d_ws;
    prep_kernel<<<48, 256, 0, stream>>>(
        (const float*)d_in[1], (const float*)d_in[2], (const float*)d_in[3],
        (const float*)d_in[4], (const float*)d_in[5],
        (const float*)d_in[6], (const float*)d_in[7], (const float*)d_in[8],
        (const float*)d_in[9], (const float*)d_in[10], ws);
    DoubleLayer_main_kernel<<<NBROWS/256, 256, 0, stream>>>(x, ws, (float*)d_out);
}